// Round 2
// baseline (1970.907 us; speedup 1.0000x reference)
//
#include <hip/hip_runtime.h>

#define TPB 256

// ---------------- CSR build (two-level counting sort for write locality) ----------------

// Pass 1: per-node degree + per-bucket (dst>>5) counts in one read of dst row.
__global__ void count_k(const int* __restrict__ ei, int* __restrict__ deg,
                        int* __restrict__ bcount, int E) {
  int e = blockIdx.x * TPB + threadIdx.x;
  if (e < E) {
    int d = ei[E + e];
    atomicAdd(&deg[d], 1);
    atomicAdd(&bcount[d >> 5], 1);
  }
}

// Generic block-wise exclusive scan (3 kernels). invd: optional (for node-degree scan).
__global__ void scan1_k(const int* __restrict__ src, int* __restrict__ out,
                        int* __restrict__ chunk, float* __restrict__ invd, int n) {
  __shared__ int sh[TPB];
  int i = blockIdx.x * TPB + threadIdx.x;
  int v = (i < n) ? src[i] : 0;
  if (invd && i < n) invd[i] = 1.0f / fmaxf((float)v, 1.0f);
  sh[threadIdx.x] = v;
  __syncthreads();
  for (int off = 1; off < TPB; off <<= 1) {
    int t = (threadIdx.x >= off) ? sh[threadIdx.x - off] : 0;
    __syncthreads();
    sh[threadIdx.x] += t;
    __syncthreads();
  }
  if (i < n) out[i] = sh[threadIdx.x] - v;  // exclusive within block
  if (threadIdx.x == TPB - 1) chunk[blockIdx.x] = sh[TPB - 1];
}

__global__ void scan2_k(int* __restrict__ chunk, int nb) {
  __shared__ int sh[512];
  int v = (threadIdx.x < nb) ? chunk[threadIdx.x] : 0;
  sh[threadIdx.x] = v;
  __syncthreads();
  for (int off = 1; off < 512; off <<= 1) {
    int t = (threadIdx.x >= off) ? sh[threadIdx.x - off] : 0;
    __syncthreads();
    sh[threadIdx.x] += t;
    __syncthreads();
  }
  if (threadIdx.x < nb) chunk[threadIdx.x] = sh[threadIdx.x] - v;  // exclusive
}

__global__ void scan3_k(int* __restrict__ out, const int* __restrict__ chunk,
                        int* __restrict__ cursor, int n) {
  int i = blockIdx.x * TPB + threadIdx.x;
  if (i < n) {
    int r = out[i] + chunk[blockIdx.x];
    out[i] = r;
    cursor[i] = r;
  }
}

// Pass 2: scatter (src,dst) into bucket-ordered edge buffer. Appends within a
// bucket are sequential -> ~3125 advancing write fronts, L2-resident lines.
__global__ void scatter_k(const int* __restrict__ ei, int* __restrict__ bcur,
                          int2* __restrict__ ebuf, int E) {
  int e = blockIdx.x * TPB + threadIdx.x;
  if (e >= E) return;
  int s = ei[e];
  int d = ei[E + e];
  int p = atomicAdd(&bcur[d >> 5], 1);
  ebuf[p] = make_int2(s, d);
}

// Pass 3: bucket-ordered edges -> final CSR. Each bucket's CSR span is ~4 KB
// and consecutive threads process the same bucket -> L2-resident writes.
__global__ void fill2_k(const int2* __restrict__ ebuf, int* __restrict__ cursor,
                        int* __restrict__ csr, int E) {
  int e = blockIdx.x * TPB + threadIdx.x;
  if (e >= E) return;
  int2 sd = ebuf[e];
  int p = atomicAdd(&cursor[sd.y], 1);
  csr[p] = sd.x;
}

// ---------------- 128-dim mean aggregation (one wave per node) ----------------

__global__ void agg128_k(const float* __restrict__ h, const int* __restrict__ csr,
                         const int* __restrict__ row_start, const int* __restrict__ deg,
                         const float* __restrict__ invd, float* __restrict__ out, int n) {
  int node = (blockIdx.x << 2) + (threadIdx.x >> 6);
  if (node >= n) return;
  int lane = threadIdx.x & 63;
  int s = row_start[node];
  int c = deg[node];
  const float2* h2 = (const float2*)h;
  float ax = 0.f, ay = 0.f;
  int j = 0;
  for (; j + 1 < c; j += 2) {
    int s0 = csr[s + j];
    int s1 = csr[s + j + 1];
    float2 v0 = h2[(size_t)s0 * 64 + lane];
    float2 v1 = h2[(size_t)s1 * 64 + lane];
    ax += v0.x + v1.x;
    ay += v0.y + v1.y;
  }
  if (j < c) {
    int s0 = csr[s + j];
    float2 v0 = h2[(size_t)s0 * 64 + lane];
    ax += v0.x; ay += v0.y;
  }
  float w = invd[node];
  float2 r; r.x = ax * w; r.y = ay * w;
  ((float2*)out)[(size_t)node * 64 + lane] = r;
}

// ---------------- fused dual GEMM: out = act(Aagg@Wl^T + Ah@Wr^T + b) ----------------
// BM=64, BN=128, BK=32, 256 threads, acc 4x8 per thread.

__global__ __launch_bounds__(256) void gemm2_k(
    const float* __restrict__ Aagg, const float* __restrict__ Ah,
    const float* __restrict__ Wl, const float* __restrict__ Wr,
    const float* __restrict__ bias, float* __restrict__ out, int n, int do_relu) {
  __shared__ float As[32 * 68];   // [k][m], stride 68 (16B aligned, conflict-light)
  __shared__ float Bs[32 * 128];  // [k][o]
  int tid = threadIdx.x;
  int m0 = blockIdx.x * 64;
  int ty = tid >> 4, tx = tid & 15;  // ty: 4-row group, tx: 8-col group
  int kgA = tid & 7, mrow = tid >> 3;     // A load mapping
  int oB = tid >> 1, halfB = tid & 1;     // B load mapping

  float acc[4][8];
#pragma unroll
  for (int i = 0; i < 4; ++i)
#pragma unroll
    for (int jj = 0; jj < 8; ++jj) acc[i][jj] = 0.f;

  for (int ks = 0; ks < 8; ++ks) {
    const float* Asrc = (ks < 4) ? Aagg : Ah;
    const float* Wsrc = (ks < 4) ? Wl : Wr;
    int kb = (ks & 3) * 32;

    // global loads to regs
    float4 aR[2];
#pragma unroll
    for (int p = 0; p < 2; ++p) {
      int row = m0 + mrow + p * 32;
      if (row < n)
        aR[p] = *(const float4*)&Asrc[(size_t)row * 128 + kb + kgA * 4];
      else
        aR[p] = make_float4(0.f, 0.f, 0.f, 0.f);
    }
    float4 bR[4];
#pragma unroll
    for (int f = 0; f < 4; ++f)
      bR[f] = *(const float4*)&Wsrc[(size_t)oB * 128 + kb + halfB * 16 + f * 4];

    __syncthreads();  // prior compute done
#pragma unroll
    for (int p = 0; p < 2; ++p) {
      float* a = (float*)&aR[p];
#pragma unroll
      for (int jj = 0; jj < 4; ++jj)
        As[(kgA * 4 + jj) * 68 + mrow + p * 32] = a[jj];
    }
#pragma unroll
    for (int f = 0; f < 4; ++f) {
      float* b = (float*)&bR[f];
#pragma unroll
      for (int jj = 0; jj < 4; ++jj)
        Bs[(halfB * 16 + f * 4 + jj) * 128 + oB] = b[jj];
    }
    __syncthreads();

#pragma unroll
    for (int k = 0; k < 32; ++k) {
      float4 a4 = *(float4*)&As[k * 68 + ty * 4];
      float4 b40 = *(float4*)&Bs[k * 128 + tx * 8];
      float4 b41 = *(float4*)&Bs[k * 128 + tx * 8 + 4];
      float av[4] = {a4.x, a4.y, a4.z, a4.w};
      float bv[8] = {b40.x, b40.y, b40.z, b40.w, b41.x, b41.y, b41.z, b41.w};
#pragma unroll
      for (int i = 0; i < 4; ++i)
#pragma unroll
        for (int jj = 0; jj < 8; ++jj) acc[i][jj] += av[i] * bv[jj];
    }
  }

  float4 bb0 = *(const float4*)&bias[tx * 8];
  float4 bb1 = *(const float4*)&bias[tx * 8 + 4];
  float bbv[8] = {bb0.x, bb0.y, bb0.z, bb0.w, bb1.x, bb1.y, bb1.z, bb1.w};
#pragma unroll
  for (int i = 0; i < 4; ++i) {
    int row = m0 + ty * 4 + i;
    if (row < n) {
      float o[8];
#pragma unroll
      for (int jj = 0; jj < 8; ++jj) {
        float v = acc[i][jj] + bbv[jj];
        o[jj] = do_relu ? fmaxf(v, 0.f) : v;
      }
      *(float4*)&out[(size_t)row * 128 + tx * 8] = make_float4(o[0], o[1], o[2], o[3]);
      *(float4*)&out[(size_t)row * 128 + tx * 8 + 4] = make_float4(o[4], o[5], o[6], o[7]);
    }
  }
}

// ---------------- head weight packing: Wcat[16][128], bcat[16] ----------------

__global__ void pack_head_k(const float* __restrict__ Wal, const float* __restrict__ War,
                            const float* __restrict__ ba, const float* __restrict__ Wsl,
                            const float* __restrict__ Wsr, const float* __restrict__ bsx,
                            const float* __restrict__ Wel, const float* __restrict__ Wer,
                            const float* __restrict__ be, float* __restrict__ Wcat,
                            float* __restrict__ bcat) {
  int t = blockIdx.x * TPB + threadIdx.x;
  if (t < 384) Wcat[t] = Wal[t];
  else if (t < 640) Wcat[t] = Wsl[t - 384];
  else if (t < 1024) Wcat[t] = Wel[t - 640];
  else if (t < 1408) Wcat[t] = War[t - 1024];
  else if (t < 1664) Wcat[t] = Wsr[t - 1408];
  else if (t < 2048) Wcat[t] = Wer[t - 1664];
  if (t < 16) {
    float b = 0.f;
    if (t >= 8 && t < 11) b = ba[t - 8];
    else if (t >= 11 && t < 13) b = bsx[t - 11];
    else if (t >= 13) b = be[t - 13];
    bcat[t] = b;
  }
}

// ---------------- head GEMM: out_lr[n,16] = h3 @ Wcat^T + bcat ----------------

__global__ __launch_bounds__(256) void head_gemm_k(const float* __restrict__ h,
                                                   const float* __restrict__ Wcat,
                                                   const float* __restrict__ bcat,
                                                   float* __restrict__ out_lr, int n) {
  __shared__ float hs[64 * 132];
  __shared__ float Ws[16 * 128];
  __shared__ float bsh[16];
  int tid = threadIdx.x;
  int m0 = blockIdx.x * 64;
  // load weights
  {
    float4 w0 = *(const float4*)&Wcat[tid * 8];
    float4 w1 = *(const float4*)&Wcat[tid * 8 + 4];
    *(float4*)&Ws[tid * 8] = w0;
    *(float4*)&Ws[tid * 8 + 4] = w1;
    if (tid < 16) bsh[tid] = bcat[tid];
  }
  // load 64 rows of h
  {
    int row = tid >> 2, q = tid & 3;
    int grow = m0 + row;
#pragma unroll
    for (int j = 0; j < 8; ++j) {
      float4 v = (grow < n) ? *(const float4*)&h[(size_t)grow * 128 + q * 32 + j * 4]
                            : make_float4(0.f, 0.f, 0.f, 0.f);
      *(float4*)&hs[row * 132 + q * 32 + j * 4] = v;
    }
  }
  __syncthreads();
  int row = tid & 63, og = tid >> 6;
  float acc[4] = {0.f, 0.f, 0.f, 0.f};
#pragma unroll
  for (int k4 = 0; k4 < 32; ++k4) {
    float4 hv = *(float4*)&hs[row * 132 + k4 * 4];
#pragma unroll
    for (int i = 0; i < 4; ++i) {
      float4 wv = *(float4*)&Ws[(og * 4 + i) * 128 + k4 * 4];
      acc[i] += hv.x * wv.x + hv.y * wv.y + hv.z * wv.z + hv.w * wv.w;
    }
  }
  int grow = m0 + row;
  if (grow < n) {
#pragma unroll
    for (int i = 0; i < 4; ++i)
      out_lr[(size_t)grow * 16 + og * 4 + i] = acc[i] + bsh[og * 4 + i];
  }
}

// ---------------- 8-dim aggregation + output write ----------------
// out layout: age [n,3] @0, sex [n,2] @3n, eth [n,3] @5n

__global__ void agg8_k(const float* __restrict__ hlr, const int* __restrict__ csr,
                       const int* __restrict__ row_start, const int* __restrict__ deg,
                       const float* __restrict__ invd, float* __restrict__ out, int n) {
  int node = (blockIdx.x << 2) + (threadIdx.x >> 6);
  if (node >= n) return;
  int lane = threadIdx.x & 63;
  int c = lane & 7, g = lane >> 3;
  int s = row_start[node], cnt = deg[node];
  float acc = 0.f;
  for (int j = g; j < cnt; j += 8) {
    int src = csr[s + j];
    acc += hlr[(size_t)src * 16 + c];
  }
  acc += __shfl_xor(acc, 8);
  acc += __shfl_xor(acc, 16);
  acc += __shfl_xor(acc, 32);
  if (g == 0) {
    float r = acc * invd[node] + hlr[(size_t)node * 16 + 8 + c];
    if (c < 3) out[(size_t)node * 3 + c] = r;
    else if (c < 5) out[(size_t)3 * n + (size_t)node * 2 + (c - 3)] = r;
    else out[(size_t)5 * n + (size_t)node * 3 + (c - 5)] = r;
  }
}

// ---------------- launch ----------------

extern "C" void kernel_launch(void* const* d_in, const int* in_sizes, int n_in,
                              void* d_out, int out_size, void* d_ws, size_t ws_size,
                              hipStream_t stream) {
  const float* x = (const float*)d_in[0];
  const int* ei = (const int*)d_in[1];
  const float* W1l = (const float*)d_in[2];
  const float* W1r = (const float*)d_in[3];
  const float* b1 = (const float*)d_in[4];
  const float* W2l = (const float*)d_in[5];
  const float* W2r = (const float*)d_in[6];
  const float* b2 = (const float*)d_in[7];
  const float* W3l = (const float*)d_in[8];
  const float* W3r = (const float*)d_in[9];
  const float* b3 = (const float*)d_in[10];
  const float* Wal = (const float*)d_in[11];
  const float* War = (const float*)d_in[12];
  const float* ba = (const float*)d_in[13];
  const float* Wsl = (const float*)d_in[14];
  const float* Wsr = (const float*)d_in[15];
  const float* bsx = (const float*)d_in[16];
  const float* Wel = (const float*)d_in[17];
  const float* Wer = (const float*)d_in[18];
  const float* be = (const float*)d_in[19];

  int N = in_sizes[0] / 128;
  int E = in_sizes[1] / 2;
  int B = (N + 31) / 32;  // dst buckets of 32 nodes

  char* w = (char*)d_ws;
  auto alloc = [&](size_t b) {
    char* p = w;
    w += (b + 255) & ~(size_t)255;
    return p;
  };
  int* deg = (int*)alloc((size_t)N * 4);
  int* row_start = (int*)alloc((size_t)N * 4);
  int* cursor = (int*)alloc((size_t)N * 4);
  int* chunk = (int*)alloc(512 * 4);
  float* invd = (float*)alloc((size_t)N * 4);
  int* bcount = (int*)alloc((size_t)B * 4);
  int* bexcl = (int*)alloc((size_t)B * 4);
  int* bcur = (int*)alloc((size_t)B * 4);
  int* csr = (int*)alloc((size_t)E * 4);
  float* aggbuf = (float*)alloc((size_t)N * 128 * 4);
  float* h_a = (float*)alloc((size_t)N * 128 * 4);
  float* h_b = (float*)alloc((size_t)N * 128 * 4);
  float* head_lr = (float*)alloc((size_t)N * 16 * 4);
  float* Wcat = (float*)alloc(16 * 128 * 4);
  float* bcat = (float*)alloc(16 * 4);
  // ebuf (E int2 = 25.6 MB) aliases aggbuf (51.2 MB): dead before first agg128 runs.
  int2* ebuf = (int2*)aggbuf;

  int nbN = (N + TPB - 1) / TPB;
  int nbB = (B + TPB - 1) / TPB;
  int nbE = (E + TPB - 1) / TPB;
  int nbNode = (N + 3) / 4;
  int nbM = (N + 63) / 64;

  hipMemsetAsync(deg, 0, (size_t)N * 4, stream);
  hipMemsetAsync(bcount, 0, (size_t)B * 4, stream);
  count_k<<<nbE, TPB, 0, stream>>>(ei, deg, bcount, E);
  // node-degree exclusive scan -> row_start, cursor, invd
  scan1_k<<<nbN, TPB, 0, stream>>>(deg, row_start, chunk, invd, N);
  scan2_k<<<1, 512, 0, stream>>>(chunk, nbN);
  scan3_k<<<nbN, TPB, 0, stream>>>(row_start, chunk, cursor, N);
  // bucket exclusive scan -> bexcl, bcur
  scan1_k<<<nbB, TPB, 0, stream>>>(bcount, bexcl, chunk, nullptr, B);
  scan2_k<<<1, 512, 0, stream>>>(chunk, nbB);
  scan3_k<<<nbB, TPB, 0, stream>>>(bexcl, chunk, bcur, B);
  // partition edges by dst bucket, then fill CSR from bucket-ordered edges
  scatter_k<<<nbE, TPB, 0, stream>>>(ei, bcur, ebuf, E);
  fill2_k<<<nbE, TPB, 0, stream>>>(ebuf, cursor, csr, E);

  // layer 1: x -> h_a
  agg128_k<<<nbNode, TPB, 0, stream>>>(x, csr, row_start, deg, invd, aggbuf, N);
  gemm2_k<<<nbM, TPB, 0, stream>>>(aggbuf, x, W1l, W1r, b1, h_a, N, 1);
  // layer 2: h_a -> h_b
  agg128_k<<<nbNode, TPB, 0, stream>>>(h_a, csr, row_start, deg, invd, aggbuf, N);
  gemm2_k<<<nbM, TPB, 0, stream>>>(aggbuf, h_a, W2l, W2r, b2, h_b, N, 1);
  // layer 3: h_b -> h_a
  agg128_k<<<nbNode, TPB, 0, stream>>>(h_b, csr, row_start, deg, invd, aggbuf, N);
  gemm2_k<<<nbM, TPB, 0, stream>>>(aggbuf, h_b, W3l, W3r, b3, h_a, N, 1);
  // heads: transform first (8 dims), then aggregate 8-dim
  pack_head_k<<<8, TPB, 0, stream>>>(Wal, War, ba, Wsl, Wsr, bsx, Wel, Wer, be, Wcat, bcat);
  head_gemm_k<<<nbM, TPB, 0, stream>>>(h_a, Wcat, bcat, head_lr, N);
  agg8_k<<<nbNode, TPB, 0, stream>>>(head_lr, csr, row_start, deg, invd, (float*)d_out, N);
}

// Round 3
// 1243.650 us; speedup vs baseline: 1.5848x; 1.5848x over previous
//
#include <hip/hip_runtime.h>

#define TPB 256
#define NB1 256    // stripe blocks for edge passes
#define NBUCK 512  // coarse buckets (dst>>8); supports N <= 131072

// ---------------- CSR build: atomic-free MSD counting sort ----------------

// Pass 1: per-block LDS histogram of coarse bucket (dst>>8).
__global__ __launch_bounds__(256) void hist1_k(const int* __restrict__ ei,
                                               int* __restrict__ hist, int E, int stripe) {
  __shared__ int h[NBUCK];
  for (int i = threadIdx.x; i < NBUCK; i += 256) h[i] = 0;
  __syncthreads();
  int b0 = blockIdx.x * stripe;
  int b1 = min(b0 + stripe, E);
  for (int e = b0 + threadIdx.x; e < b1; e += 256) atomicAdd(&h[ei[E + e] >> 8], 1);
  __syncthreads();
  for (int i = threadIdx.x; i < NBUCK; i += 256) hist[i * NB1 + blockIdx.x] = h[i];
}

// Generic block-wise exclusive scan (3 kernels).
__global__ void scan1_k(const int* __restrict__ src, int* __restrict__ out,
                        int* __restrict__ chunk, int n) {
  __shared__ int sh[TPB];
  int i = blockIdx.x * TPB + threadIdx.x;
  int v = (i < n) ? src[i] : 0;
  sh[threadIdx.x] = v;
  __syncthreads();
  for (int off = 1; off < TPB; off <<= 1) {
    int t = (threadIdx.x >= off) ? sh[threadIdx.x - off] : 0;
    __syncthreads();
    sh[threadIdx.x] += t;
    __syncthreads();
  }
  if (i < n) out[i] = sh[threadIdx.x] - v;  // exclusive within block
  if (threadIdx.x == TPB - 1) chunk[blockIdx.x] = sh[TPB - 1];
}

__global__ void scan2_k(int* __restrict__ chunk, int nb) {
  __shared__ int sh[512];
  int v = (threadIdx.x < nb) ? chunk[threadIdx.x] : 0;
  sh[threadIdx.x] = v;
  __syncthreads();
  for (int off = 1; off < 512; off <<= 1) {
    int t = (threadIdx.x >= off) ? sh[threadIdx.x - off] : 0;
    __syncthreads();
    sh[threadIdx.x] += t;
    __syncthreads();
  }
  if (threadIdx.x < nb) chunk[threadIdx.x] = sh[threadIdx.x] - v;  // exclusive
}

__global__ void scan3_k(int* __restrict__ out, const int* __restrict__ chunk, int n) {
  int i = blockIdx.x * TPB + threadIdx.x;
  if (i < n) out[i] += chunk[blockIdx.x];
}

// Pass 2: scatter edges into coarse-bucket-ordered buffer; cursors live in LDS.
// pack: src (24 bits, N<2^17) | low8(dst) << 24
__global__ __launch_bounds__(256) void scatter1_k(const int* __restrict__ ei,
                                                  const int* __restrict__ base,
                                                  unsigned* __restrict__ ebuf, int E,
                                                  int stripe) {
  __shared__ int cur[NBUCK];
  for (int i = threadIdx.x; i < NBUCK; i += 256) cur[i] = base[i * NB1 + blockIdx.x];
  __syncthreads();
  int b0 = blockIdx.x * stripe;
  int b1 = min(b0 + stripe, E);
  for (int e = b0 + threadIdx.x; e < b1; e += 256) {
    int s = ei[e];
    int d = ei[E + e];
    int p = atomicAdd(&cur[d >> 8], 1);
    ebuf[p] = (unsigned)s | ((unsigned)(d & 255) << 24);
  }
}

// Pass 3: one block per coarse bucket. LDS histogram of low8(dst) -> deg/row_start/invd
// + final CSR scatter. No global atomics anywhere.
__global__ __launch_bounds__(256) void build_k(const unsigned* __restrict__ ebuf,
                                               const int* __restrict__ base,
                                               int* __restrict__ row_start,
                                               int* __restrict__ deg,
                                               float* __restrict__ invd,
                                               int* __restrict__ csr, int N, int E) {
  __shared__ int h[256];
  __shared__ int excl[256];
  __shared__ int bse[2];
  int b = blockIdx.x;
  int t = threadIdx.x;
  if (t == 0) {
    bse[0] = base[b * NB1];
    bse[1] = (b + 1 < NBUCK) ? base[(b + 1) * NB1] : E;
  }
  h[t] = 0;
  __syncthreads();
  int bs = bse[0], be = bse[1];
  for (int e = bs + t; e < be; e += 256) atomicAdd(&h[ebuf[e] >> 24], 1);
  __syncthreads();
  int v = h[t];
  excl[t] = v;
  __syncthreads();
  for (int off = 1; off < 256; off <<= 1) {
    int tv = (t >= off) ? excl[t - off] : 0;
    __syncthreads();
    excl[t] += tv;
    __syncthreads();
  }
  int ex = excl[t] - v;  // exclusive
  int node = b * 256 + t;
  if (node < N) {
    row_start[node] = bs + ex;
    deg[node] = v;
    invd[node] = 1.0f / fmaxf((float)v, 1.0f);
  }
  h[t] = bs + ex;  // reuse as cursor
  __syncthreads();
  for (int e = bs + t; e < be; e += 256) {
    unsigned p = ebuf[e];
    int pos = atomicAdd(&h[p >> 24], 1);
    csr[pos] = (int)(p & 0xFFFFFFu);
  }
}

// ---------------- 128-dim mean aggregation (one wave per node) ----------------

__global__ void agg128_k(const float* __restrict__ h, const int* __restrict__ csr,
                         const int* __restrict__ row_start, const int* __restrict__ deg,
                         const float* __restrict__ invd, float* __restrict__ out, int n) {
  int node = (blockIdx.x << 2) + (threadIdx.x >> 6);
  if (node >= n) return;
  int lane = threadIdx.x & 63;
  int s = row_start[node];
  int c = deg[node];
  const float2* h2 = (const float2*)h;
  float ax = 0.f, ay = 0.f;
  int j = 0;
  for (; j + 1 < c; j += 2) {
    int s0 = csr[s + j];
    int s1 = csr[s + j + 1];
    float2 v0 = h2[(size_t)s0 * 64 + lane];
    float2 v1 = h2[(size_t)s1 * 64 + lane];
    ax += v0.x + v1.x;
    ay += v0.y + v1.y;
  }
  if (j < c) {
    int s0 = csr[s + j];
    float2 v0 = h2[(size_t)s0 * 64 + lane];
    ax += v0.x; ay += v0.y;
  }
  float w = invd[node];
  float2 r; r.x = ax * w; r.y = ay * w;
  ((float2*)out)[(size_t)node * 64 + lane] = r;
}

// ---------------- fused dual GEMM: out = act(Aagg@Wl^T + Ah@Wr^T + b) ----------------
// BM=64, BN=128, BK=32, 256 threads, acc 4x8 per thread.

__global__ __launch_bounds__(256) void gemm2_k(
    const float* __restrict__ Aagg, const float* __restrict__ Ah,
    const float* __restrict__ Wl, const float* __restrict__ Wr,
    const float* __restrict__ bias, float* __restrict__ out, int n, int do_relu) {
  __shared__ float As[32 * 68];   // [k][m], stride 68 (16B aligned, conflict-light)
  __shared__ float Bs[32 * 128];  // [k][o]
  int tid = threadIdx.x;
  int m0 = blockIdx.x * 64;
  int ty = tid >> 4, tx = tid & 15;  // ty: 4-row group, tx: 8-col group
  int kgA = tid & 7, mrow = tid >> 3;     // A load mapping
  int oB = tid >> 1, halfB = tid & 1;     // B load mapping

  float acc[4][8];
#pragma unroll
  for (int i = 0; i < 4; ++i)
#pragma unroll
    for (int jj = 0; jj < 8; ++jj) acc[i][jj] = 0.f;

  for (int ks = 0; ks < 8; ++ks) {
    const float* Asrc = (ks < 4) ? Aagg : Ah;
    const float* Wsrc = (ks < 4) ? Wl : Wr;
    int kb = (ks & 3) * 32;

    // global loads to regs
    float4 aR[2];
#pragma unroll
    for (int p = 0; p < 2; ++p) {
      int row = m0 + mrow + p * 32;
      if (row < n)
        aR[p] = *(const float4*)&Asrc[(size_t)row * 128 + kb + kgA * 4];
      else
        aR[p] = make_float4(0.f, 0.f, 0.f, 0.f);
    }
    float4 bR[4];
#pragma unroll
    for (int f = 0; f < 4; ++f)
      bR[f] = *(const float4*)&Wsrc[(size_t)oB * 128 + kb + halfB * 16 + f * 4];

    __syncthreads();  // prior compute done
#pragma unroll
    for (int p = 0; p < 2; ++p) {
      float* a = (float*)&aR[p];
#pragma unroll
      for (int jj = 0; jj < 4; ++jj)
        As[(kgA * 4 + jj) * 68 + mrow + p * 32] = a[jj];
    }
#pragma unroll
    for (int f = 0; f < 4; ++f) {
      float* b = (float*)&bR[f];
#pragma unroll
      for (int jj = 0; jj < 4; ++jj)
        Bs[(halfB * 16 + f * 4 + jj) * 128 + oB] = b[jj];
    }
    __syncthreads();

#pragma unroll
    for (int k = 0; k < 32; ++k) {
      float4 a4 = *(float4*)&As[k * 68 + ty * 4];
      float4 b40 = *(float4*)&Bs[k * 128 + tx * 8];
      float4 b41 = *(float4*)&Bs[k * 128 + tx * 8 + 4];
      float av[4] = {a4.x, a4.y, a4.z, a4.w};
      float bv[8] = {b40.x, b40.y, b40.z, b40.w, b41.x, b41.y, b41.z, b41.w};
#pragma unroll
      for (int i = 0; i < 4; ++i)
#pragma unroll
        for (int jj = 0; jj < 8; ++jj) acc[i][jj] += av[i] * bv[jj];
    }
  }

  float4 bb0 = *(const float4*)&bias[tx * 8];
  float4 bb1 = *(const float4*)&bias[tx * 8 + 4];
  float bbv[8] = {bb0.x, bb0.y, bb0.z, bb0.w, bb1.x, bb1.y, bb1.z, bb1.w};
#pragma unroll
  for (int i = 0; i < 4; ++i) {
    int row = m0 + ty * 4 + i;
    if (row < n) {
      float o[8];
#pragma unroll
      for (int jj = 0; jj < 8; ++jj) {
        float v = acc[i][jj] + bbv[jj];
        o[jj] = do_relu ? fmaxf(v, 0.f) : v;
      }
      *(float4*)&out[(size_t)row * 128 + tx * 8] = make_float4(o[0], o[1], o[2], o[3]);
      *(float4*)&out[(size_t)row * 128 + tx * 8 + 4] = make_float4(o[4], o[5], o[6], o[7]);
    }
  }
}

// ---------------- head weight packing: Wcat[16][128], bcat[16] ----------------

__global__ void pack_head_k(const float* __restrict__ Wal, const float* __restrict__ War,
                            const float* __restrict__ ba, const float* __restrict__ Wsl,
                            const float* __restrict__ Wsr, const float* __restrict__ bsx,
                            const float* __restrict__ Wel, const float* __restrict__ Wer,
                            const float* __restrict__ be, float* __restrict__ Wcat,
                            float* __restrict__ bcat) {
  int t = blockIdx.x * TPB + threadIdx.x;
  if (t < 384) Wcat[t] = Wal[t];
  else if (t < 640) Wcat[t] = Wsl[t - 384];
  else if (t < 1024) Wcat[t] = Wel[t - 640];
  else if (t < 1408) Wcat[t] = War[t - 1024];
  else if (t < 1664) Wcat[t] = Wsr[t - 1408];
  else if (t < 2048) Wcat[t] = Wer[t - 1664];
  if (t < 16) {
    float b = 0.f;
    if (t >= 8 && t < 11) b = ba[t - 8];
    else if (t >= 11 && t < 13) b = bsx[t - 11];
    else if (t >= 13) b = be[t - 13];
    bcat[t] = b;
  }
}

// ---------------- head GEMM: out_lr[n,16] = h3 @ Wcat^T + bcat ----------------

__global__ __launch_bounds__(256) void head_gemm_k(const float* __restrict__ h,
                                                   const float* __restrict__ Wcat,
                                                   const float* __restrict__ bcat,
                                                   float* __restrict__ out_lr, int n) {
  __shared__ float hs[64 * 132];
  __shared__ float Ws[16 * 128];
  __shared__ float bsh[16];
  int tid = threadIdx.x;
  int m0 = blockIdx.x * 64;
  // load weights
  {
    float4 w0 = *(const float4*)&Wcat[tid * 8];
    float4 w1 = *(const float4*)&Wcat[tid * 8 + 4];
    *(float4*)&Ws[tid * 8] = w0;
    *(float4*)&Ws[tid * 8 + 4] = w1;
    if (tid < 16) bsh[tid] = bcat[tid];
  }
  // load 64 rows of h
  {
    int row = tid >> 2, q = tid & 3;
    int grow = m0 + row;
#pragma unroll
    for (int j = 0; j < 8; ++j) {
      float4 v = (grow < n) ? *(const float4*)&h[(size_t)grow * 128 + q * 32 + j * 4]
                            : make_float4(0.f, 0.f, 0.f, 0.f);
      *(float4*)&hs[row * 132 + q * 32 + j * 4] = v;
    }
  }
  __syncthreads();
  int row = tid & 63, og = tid >> 6;
  float acc[4] = {0.f, 0.f, 0.f, 0.f};
#pragma unroll
  for (int k4 = 0; k4 < 32; ++k4) {
    float4 hv = *(float4*)&hs[row * 132 + k4 * 4];
#pragma unroll
    for (int i = 0; i < 4; ++i) {
      float4 wv = *(float4*)&Ws[(og * 4 + i) * 128 + k4 * 4];
      acc[i] += hv.x * wv.x + hv.y * wv.y + hv.z * wv.z + hv.w * wv.w;
    }
  }
  int grow = m0 + row;
  if (grow < n) {
#pragma unroll
    for (int i = 0; i < 4; ++i)
      out_lr[(size_t)grow * 16 + og * 4 + i] = acc[i] + bsh[og * 4 + i];
  }
}

// ---------------- 8-dim aggregation + output write ----------------
// out layout: age [n,3] @0, sex [n,2] @3n, eth [n,3] @5n

__global__ void agg8_k(const float* __restrict__ hlr, const int* __restrict__ csr,
                       const int* __restrict__ row_start, const int* __restrict__ deg,
                       const float* __restrict__ invd, float* __restrict__ out, int n) {
  int node = (blockIdx.x << 2) + (threadIdx.x >> 6);
  if (node >= n) return;
  int lane = threadIdx.x & 63;
  int c = lane & 7, g = lane >> 3;
  int s = row_start[node], cnt = deg[node];
  float acc = 0.f;
  for (int j = g; j < cnt; j += 8) {
    int src = csr[s + j];
    acc += hlr[(size_t)src * 16 + c];
  }
  acc += __shfl_xor(acc, 8);
  acc += __shfl_xor(acc, 16);
  acc += __shfl_xor(acc, 32);
  if (g == 0) {
    float r = acc * invd[node] + hlr[(size_t)node * 16 + 8 + c];
    if (c < 3) out[(size_t)node * 3 + c] = r;
    else if (c < 5) out[(size_t)3 * n + (size_t)node * 2 + (c - 3)] = r;
    else out[(size_t)5 * n + (size_t)node * 3 + (c - 5)] = r;
  }
}

// ---------------- launch ----------------

extern "C" void kernel_launch(void* const* d_in, const int* in_sizes, int n_in,
                              void* d_out, int out_size, void* d_ws, size_t ws_size,
                              hipStream_t stream) {
  const float* x = (const float*)d_in[0];
  const int* ei = (const int*)d_in[1];
  const float* W1l = (const float*)d_in[2];
  const float* W1r = (const float*)d_in[3];
  const float* b1 = (const float*)d_in[4];
  const float* W2l = (const float*)d_in[5];
  const float* W2r = (const float*)d_in[6];
  const float* b2 = (const float*)d_in[7];
  const float* W3l = (const float*)d_in[8];
  const float* W3r = (const float*)d_in[9];
  const float* b3 = (const float*)d_in[10];
  const float* Wal = (const float*)d_in[11];
  const float* War = (const float*)d_in[12];
  const float* ba = (const float*)d_in[13];
  const float* Wsl = (const float*)d_in[14];
  const float* Wsr = (const float*)d_in[15];
  const float* bsx = (const float*)d_in[16];
  const float* Wel = (const float*)d_in[17];
  const float* Wer = (const float*)d_in[18];
  const float* be = (const float*)d_in[19];

  int N = in_sizes[0] / 128;
  int E = in_sizes[1] / 2;
  int NBKT = (N + 255) >> 8;  // used coarse buckets

  char* w = (char*)d_ws;
  auto alloc = [&](size_t b) {
    char* p = w;
    w += (b + 255) & ~(size_t)255;
    return p;
  };
  int* deg = (int*)alloc((size_t)N * 4);
  int* row_start = (int*)alloc((size_t)N * 4);
  float* invd = (float*)alloc((size_t)N * 4);
  int* hist = (int*)alloc((size_t)NBUCK * NB1 * 4);  // doubles as base after scan
  int* chunk = (int*)alloc(512 * 4);
  int* csr = (int*)alloc((size_t)E * 4);
  unsigned* ebuf = (unsigned*)alloc((size_t)E * 4);
  float* aggbuf = (float*)alloc((size_t)N * 128 * 4);
  float* h_a = (float*)alloc((size_t)N * 128 * 4);
  float* h_b = (float*)alloc((size_t)N * 128 * 4);
  float* head_lr = (float*)alloc((size_t)N * 16 * 4);
  float* Wcat = (float*)alloc(16 * 128 * 4);
  float* bcat = (float*)alloc(16 * 4);

  int stripe = (((E + NB1 - 1) / NB1) + 255) & ~255;
  int nscan = NBUCK * NB1;                  // 131072
  int nbScan = (nscan + TPB - 1) / TPB;     // 512
  int nbNode = (N + 3) / 4;
  int nbM = (N + 63) / 64;

  // CSR build — no global atomics
  hist1_k<<<NB1, 256, 0, stream>>>(ei, hist, E, stripe);
  scan1_k<<<nbScan, TPB, 0, stream>>>(hist, hist, chunk, nscan);
  scan2_k<<<1, 512, 0, stream>>>(chunk, nbScan);
  scan3_k<<<nbScan, TPB, 0, stream>>>(hist, chunk, nscan);
  scatter1_k<<<NB1, 256, 0, stream>>>(ei, hist, ebuf, E, stripe);
  build_k<<<NBKT, 256, 0, stream>>>(ebuf, hist, row_start, deg, invd, csr, N, E);

  // layer 1: x -> h_a
  agg128_k<<<nbNode, TPB, 0, stream>>>(x, csr, row_start, deg, invd, aggbuf, N);
  gemm2_k<<<nbM, TPB, 0, stream>>>(aggbuf, x, W1l, W1r, b1, h_a, N, 1);
  // layer 2: h_a -> h_b
  agg128_k<<<nbNode, TPB, 0, stream>>>(h_a, csr, row_start, deg, invd, aggbuf, N);
  gemm2_k<<<nbM, TPB, 0, stream>>>(aggbuf, h_a, W2l, W2r, b2, h_b, N, 1);
  // layer 3: h_b -> h_a
  agg128_k<<<nbNode, TPB, 0, stream>>>(h_b, csr, row_start, deg, invd, aggbuf, N);
  gemm2_k<<<nbM, TPB, 0, stream>>>(aggbuf, h_b, W3l, W3r, b3, h_a, N, 1);
  // heads: transform first (8 dims), then aggregate 8-dim
  pack_head_k<<<8, TPB, 0, stream>>>(Wal, War, ba, Wsl, Wsr, bsx, Wel, Wer, be, Wcat, bcat);
  head_gemm_k<<<nbM, TPB, 0, stream>>>(h_a, Wcat, bcat, head_lr, N);
  agg8_k<<<nbNode, TPB, 0, stream>>>(head_lr, csr, row_start, deg, invd, (float*)d_out, N);
}

// Round 4
// 929.204 us; speedup vs baseline: 2.1211x; 1.3384x over previous
//
#include <hip/hip_runtime.h>

#define TPB 256
#define NB1 256    // stripe blocks for edge passes
#define NBUCK 512  // coarse buckets (dst>>8); supports N <= 131072

static __device__ __forceinline__ unsigned short f2bf(float f) {
  unsigned u = __float_as_uint(f);
  unsigned r = (u + 0x7FFF + ((u >> 16) & 1)) >> 16;  // RNE
  return (unsigned short)r;
}
static __device__ __forceinline__ float bf2f(unsigned short b) {
  return __uint_as_float((unsigned)b << 16);
}

// ---------------- CSR build: atomic-free MSD counting sort ----------------

__global__ __launch_bounds__(256) void hist1_k(const int* __restrict__ ei,
                                               int* __restrict__ hist, int E, int stripe) {
  __shared__ int h[NBUCK];
  for (int i = threadIdx.x; i < NBUCK; i += 256) h[i] = 0;
  __syncthreads();
  int b0 = blockIdx.x * stripe;
  int b1 = min(b0 + stripe, E);
  for (int e = b0 + threadIdx.x; e < b1; e += 256) atomicAdd(&h[ei[E + e] >> 8], 1);
  __syncthreads();
  for (int i = threadIdx.x; i < NBUCK; i += 256) hist[i * NB1 + blockIdx.x] = h[i];
}

__global__ void scan1_k(const int* __restrict__ src, int* __restrict__ out,
                        int* __restrict__ chunk, int n) {
  __shared__ int sh[TPB];
  int i = blockIdx.x * TPB + threadIdx.x;
  int v = (i < n) ? src[i] : 0;
  sh[threadIdx.x] = v;
  __syncthreads();
  for (int off = 1; off < TPB; off <<= 1) {
    int t = (threadIdx.x >= off) ? sh[threadIdx.x - off] : 0;
    __syncthreads();
    sh[threadIdx.x] += t;
    __syncthreads();
  }
  if (i < n) out[i] = sh[threadIdx.x] - v;
  if (threadIdx.x == TPB - 1) chunk[blockIdx.x] = sh[TPB - 1];
}

__global__ void scan2_k(int* __restrict__ chunk, int nb) {
  __shared__ int sh[512];
  int v = (threadIdx.x < nb) ? chunk[threadIdx.x] : 0;
  sh[threadIdx.x] = v;
  __syncthreads();
  for (int off = 1; off < 512; off <<= 1) {
    int t = (threadIdx.x >= off) ? sh[threadIdx.x - off] : 0;
    __syncthreads();
    sh[threadIdx.x] += t;
    __syncthreads();
  }
  if (threadIdx.x < nb) chunk[threadIdx.x] = sh[threadIdx.x] - v;
}

__global__ void scan3_k(int* __restrict__ out, const int* __restrict__ chunk, int n) {
  int i = blockIdx.x * TPB + threadIdx.x;
  if (i < n) out[i] += chunk[blockIdx.x];
}

// pack: src (24 bits, N<2^17... N<=2^24 ok) | low8(dst) << 24
__global__ __launch_bounds__(256) void scatter1_k(const int* __restrict__ ei,
                                                  const int* __restrict__ base,
                                                  unsigned* __restrict__ ebuf, int E,
                                                  int stripe) {
  __shared__ int cur[NBUCK];
  for (int i = threadIdx.x; i < NBUCK; i += 256) cur[i] = base[i * NB1 + blockIdx.x];
  __syncthreads();
  int b0 = blockIdx.x * stripe;
  int b1 = min(b0 + stripe, E);
  for (int e = b0 + threadIdx.x; e < b1; e += 256) {
    int s = ei[e];
    int d = ei[E + e];
    int p = atomicAdd(&cur[d >> 8], 1);
    ebuf[p] = (unsigned)s | ((unsigned)(d & 255) << 24);
  }
}

__global__ __launch_bounds__(256) void build_k(const unsigned* __restrict__ ebuf,
                                               const int* __restrict__ base,
                                               int* __restrict__ row_start,
                                               int* __restrict__ deg,
                                               float* __restrict__ invd,
                                               int* __restrict__ csr, int N, int E) {
  __shared__ int h[256];
  __shared__ int excl[256];
  __shared__ int bse[2];
  int b = blockIdx.x;
  int t = threadIdx.x;
  if (t == 0) {
    bse[0] = base[b * NB1];
    bse[1] = (b + 1 < NBUCK) ? base[(b + 1) * NB1] : E;
  }
  h[t] = 0;
  __syncthreads();
  int bs = bse[0], be = bse[1];
  for (int e = bs + t; e < be; e += 256) atomicAdd(&h[ebuf[e] >> 24], 1);
  __syncthreads();
  int v = h[t];
  excl[t] = v;
  __syncthreads();
  for (int off = 1; off < 256; off <<= 1) {
    int tv = (t >= off) ? excl[t - off] : 0;
    __syncthreads();
    excl[t] += tv;
    __syncthreads();
  }
  int ex = excl[t] - v;
  int node = b * 256 + t;
  if (node < N) {
    row_start[node] = bs + ex;
    deg[node] = v;
    invd[node] = 1.0f / fmaxf((float)v, 1.0f);
  }
  h[t] = bs + ex;
  __syncthreads();
  for (int e = bs + t; e < be; e += 256) {
    unsigned p = ebuf[e];
    int pos = atomicAdd(&h[p >> 24], 1);
    csr[pos] = (int)(p & 0xFFFFFFu);
  }
}

// ---------------- fp32 -> bf16 convert ----------------

__global__ void f2b_k(const float* __restrict__ in, unsigned short* __restrict__ out,
                      int n4) {
  int i = blockIdx.x * TPB + threadIdx.x;
  if (i < n4) {
    float4 v = ((const float4*)in)[i];
    ushort4 o;
    o.x = f2bf(v.x); o.y = f2bf(v.y); o.z = f2bf(v.z); o.w = f2bf(v.w);
    ((ushort4*)out)[i] = o;
  }
}

// ---------------- 128-dim mean aggregation, bf16 gather ----------------
// One wave per node; lanes 0-31 handle even rows, 32-63 odd rows.
// Lane (l = lane&31) covers features l*4..l*4+3 (ushort4 = 8B per load).

__global__ void agg128_k(const unsigned short* __restrict__ hb, const int* __restrict__ csr,
                         const int* __restrict__ row_start, const int* __restrict__ deg,
                         const float* __restrict__ invd, float* __restrict__ out, int n) {
  int node = (blockIdx.x << 2) + (threadIdx.x >> 6);
  if (node >= n) return;
  int lane = threadIdx.x & 63;
  int half = lane >> 5;
  int l = lane & 31;
  int s = row_start[node];
  int c = deg[node];
  float a0 = 0.f, a1 = 0.f, a2 = 0.f, a3 = 0.f;
  int j = 0;
  for (; j + 8 <= c; j += 8) {
    int idx[4];
#pragma unroll
    for (int p = 0; p < 4; ++p) idx[p] = csr[s + j + 2 * p + half];
#pragma unroll
    for (int p = 0; p < 4; ++p) {
      ushort4 v = *(const ushort4*)&hb[(size_t)idx[p] * 128 + (l << 2)];
      a0 += bf2f(v.x); a1 += bf2f(v.y); a2 += bf2f(v.z); a3 += bf2f(v.w);
    }
  }
  for (; j + 2 <= c; j += 2) {
    int src = csr[s + j + half];
    ushort4 v = *(const ushort4*)&hb[(size_t)src * 128 + (l << 2)];
    a0 += bf2f(v.x); a1 += bf2f(v.y); a2 += bf2f(v.z); a3 += bf2f(v.w);
  }
  if (j < c && half == 0) {
    int src = csr[s + j];
    ushort4 v = *(const ushort4*)&hb[(size_t)src * 128 + (l << 2)];
    a0 += bf2f(v.x); a1 += bf2f(v.y); a2 += bf2f(v.z); a3 += bf2f(v.w);
  }
  // combine the two half-wave partials
  a0 += __shfl_xor(a0, 32);
  a1 += __shfl_xor(a1, 32);
  a2 += __shfl_xor(a2, 32);
  a3 += __shfl_xor(a3, 32);
  if (half == 0) {
    float w = invd[node];
    *(float4*)&out[(size_t)node * 128 + (l << 2)] =
        make_float4(a0 * w, a1 * w, a2 * w, a3 * w);
  }
}

// ---------------- fused dual GEMM: out = act(Aagg@Wl^T + Ah@Wr^T + b) ----------------
// Writes fp32 result and bf16 copy (for the next layer's gather).

__global__ __launch_bounds__(256) void gemm2_k(
    const float* __restrict__ Aagg, const float* __restrict__ Ah,
    const float* __restrict__ Wl, const float* __restrict__ Wr,
    const float* __restrict__ bias, float* __restrict__ out,
    unsigned short* __restrict__ outb, int n, int do_relu) {
  __shared__ float As[32 * 68];
  __shared__ float Bs[32 * 128];
  int tid = threadIdx.x;
  int m0 = blockIdx.x * 64;
  int ty = tid >> 4, tx = tid & 15;
  int kgA = tid & 7, mrow = tid >> 3;
  int oB = tid >> 1, halfB = tid & 1;

  float acc[4][8];
#pragma unroll
  for (int i = 0; i < 4; ++i)
#pragma unroll
    for (int jj = 0; jj < 8; ++jj) acc[i][jj] = 0.f;

  for (int ks = 0; ks < 8; ++ks) {
    const float* Asrc = (ks < 4) ? Aagg : Ah;
    const float* Wsrc = (ks < 4) ? Wl : Wr;
    int kb = (ks & 3) * 32;

    float4 aR[2];
#pragma unroll
    for (int p = 0; p < 2; ++p) {
      int row = m0 + mrow + p * 32;
      if (row < n)
        aR[p] = *(const float4*)&Asrc[(size_t)row * 128 + kb + kgA * 4];
      else
        aR[p] = make_float4(0.f, 0.f, 0.f, 0.f);
    }
    float4 bR[4];
#pragma unroll
    for (int f = 0; f < 4; ++f)
      bR[f] = *(const float4*)&Wsrc[(size_t)oB * 128 + kb + halfB * 16 + f * 4];

    __syncthreads();
#pragma unroll
    for (int p = 0; p < 2; ++p) {
      float* a = (float*)&aR[p];
#pragma unroll
      for (int jj = 0; jj < 4; ++jj)
        As[(kgA * 4 + jj) * 68 + mrow + p * 32] = a[jj];
    }
#pragma unroll
    for (int f = 0; f < 4; ++f) {
      float* b = (float*)&bR[f];
#pragma unroll
      for (int jj = 0; jj < 4; ++jj)
        Bs[(halfB * 16 + f * 4 + jj) * 128 + oB] = b[jj];
    }
    __syncthreads();

#pragma unroll
    for (int k = 0; k < 32; ++k) {
      float4 a4 = *(float4*)&As[k * 68 + ty * 4];
      float4 b40 = *(float4*)&Bs[k * 128 + tx * 8];
      float4 b41 = *(float4*)&Bs[k * 128 + tx * 8 + 4];
      float av[4] = {a4.x, a4.y, a4.z, a4.w};
      float bv[8] = {b40.x, b40.y, b40.z, b40.w, b41.x, b41.y, b41.z, b41.w};
#pragma unroll
      for (int i = 0; i < 4; ++i)
#pragma unroll
        for (int jj = 0; jj < 8; ++jj) acc[i][jj] += av[i] * bv[jj];
    }
  }

  float4 bb0 = *(const float4*)&bias[tx * 8];
  float4 bb1 = *(const float4*)&bias[tx * 8 + 4];
  float bbv[8] = {bb0.x, bb0.y, bb0.z, bb0.w, bb1.x, bb1.y, bb1.z, bb1.w};
#pragma unroll
  for (int i = 0; i < 4; ++i) {
    int row = m0 + ty * 4 + i;
    if (row < n) {
      float o[8];
#pragma unroll
      for (int jj = 0; jj < 8; ++jj) {
        float v = acc[i][jj] + bbv[jj];
        o[jj] = do_relu ? fmaxf(v, 0.f) : v;
      }
      *(float4*)&out[(size_t)row * 128 + tx * 8] = make_float4(o[0], o[1], o[2], o[3]);
      *(float4*)&out[(size_t)row * 128 + tx * 8 + 4] = make_float4(o[4], o[5], o[6], o[7]);
      uint4 ub;
      ub.x = (unsigned)f2bf(o[0]) | ((unsigned)f2bf(o[1]) << 16);
      ub.y = (unsigned)f2bf(o[2]) | ((unsigned)f2bf(o[3]) << 16);
      ub.z = (unsigned)f2bf(o[4]) | ((unsigned)f2bf(o[5]) << 16);
      ub.w = (unsigned)f2bf(o[6]) | ((unsigned)f2bf(o[7]) << 16);
      *(uint4*)&outb[(size_t)row * 128 + tx * 8] = ub;
    }
  }
}

// ---------------- head weight packing ----------------

__global__ void pack_head_k(const float* __restrict__ Wal, const float* __restrict__ War,
                            const float* __restrict__ ba, const float* __restrict__ Wsl,
                            const float* __restrict__ Wsr, const float* __restrict__ bsx,
                            const float* __restrict__ Wel, const float* __restrict__ Wer,
                            const float* __restrict__ be, float* __restrict__ Wcat,
                            float* __restrict__ bcat) {
  int t = blockIdx.x * TPB + threadIdx.x;
  if (t < 384) Wcat[t] = Wal[t];
  else if (t < 640) Wcat[t] = Wsl[t - 384];
  else if (t < 1024) Wcat[t] = Wel[t - 640];
  else if (t < 1408) Wcat[t] = War[t - 1024];
  else if (t < 1664) Wcat[t] = Wsr[t - 1408];
  else if (t < 2048) Wcat[t] = Wer[t - 1664];
  if (t < 16) {
    float b = 0.f;
    if (t >= 8 && t < 11) b = ba[t - 8];
    else if (t >= 11 && t < 13) b = bsx[t - 11];
    else if (t >= 13) b = be[t - 13];
    bcat[t] = b;
  }
}

// ---------------- head GEMM: out_lr[n,16] = h3 @ Wcat^T + bcat ----------------

__global__ __launch_bounds__(256) void head_gemm_k(const float* __restrict__ h,
                                                   const float* __restrict__ Wcat,
                                                   const float* __restrict__ bcat,
                                                   float* __restrict__ out_lr, int n) {
  __shared__ float hs[64 * 132];
  __shared__ float Ws[16 * 128];
  __shared__ float bsh[16];
  int tid = threadIdx.x;
  int m0 = blockIdx.x * 64;
  {
    float4 w0 = *(const float4*)&Wcat[tid * 8];
    float4 w1 = *(const float4*)&Wcat[tid * 8 + 4];
    *(float4*)&Ws[tid * 8] = w0;
    *(float4*)&Ws[tid * 8 + 4] = w1;
    if (tid < 16) bsh[tid] = bcat[tid];
  }
  {
    int row = tid >> 2, q = tid & 3;
    int grow = m0 + row;
#pragma unroll
    for (int j = 0; j < 8; ++j) {
      float4 v = (grow < n) ? *(const float4*)&h[(size_t)grow * 128 + q * 32 + j * 4]
                            : make_float4(0.f, 0.f, 0.f, 0.f);
      *(float4*)&hs[row * 132 + q * 32 + j * 4] = v;
    }
  }
  __syncthreads();
  int row = tid & 63, og = tid >> 6;
  float acc[4] = {0.f, 0.f, 0.f, 0.f};
#pragma unroll
  for (int k4 = 0; k4 < 32; ++k4) {
    float4 hv = *(float4*)&hs[row * 132 + k4 * 4];
#pragma unroll
    for (int i = 0; i < 4; ++i) {
      float4 wv = *(float4*)&Ws[(og * 4 + i) * 128 + k4 * 4];
      acc[i] += hv.x * wv.x + hv.y * wv.y + hv.z * wv.z + hv.w * wv.w;
    }
  }
  int grow = m0 + row;
  if (grow < n) {
#pragma unroll
    for (int i = 0; i < 4; ++i)
      out_lr[(size_t)grow * 16 + og * 4 + i] = acc[i] + bsh[og * 4 + i];
  }
}

// ---------------- 8-dim aggregation + output write ----------------

__global__ void agg8_k(const float* __restrict__ hlr, const int* __restrict__ csr,
                       const int* __restrict__ row_start, const int* __restrict__ deg,
                       const float* __restrict__ invd, float* __restrict__ out, int n) {
  int node = (blockIdx.x << 2) + (threadIdx.x >> 6);
  if (node >= n) return;
  int lane = threadIdx.x & 63;
  int c = lane & 7, g = lane >> 3;
  int s = row_start[node], cnt = deg[node];
  float acc = 0.f;
  for (int j = g; j < cnt; j += 8) {
    int src = csr[s + j];
    acc += hlr[(size_t)src * 16 + c];
  }
  acc += __shfl_xor(acc, 8);
  acc += __shfl_xor(acc, 16);
  acc += __shfl_xor(acc, 32);
  if (g == 0) {
    float r = acc * invd[node] + hlr[(size_t)node * 16 + 8 + c];
    if (c < 3) out[(size_t)node * 3 + c] = r;
    else if (c < 5) out[(size_t)3 * n + (size_t)node * 2 + (c - 3)] = r;
    else out[(size_t)5 * n + (size_t)node * 3 + (c - 5)] = r;
  }
}

// ---------------- launch ----------------

extern "C" void kernel_launch(void* const* d_in, const int* in_sizes, int n_in,
                              void* d_out, int out_size, void* d_ws, size_t ws_size,
                              hipStream_t stream) {
  const float* x = (const float*)d_in[0];
  const int* ei = (const int*)d_in[1];
  const float* W1l = (const float*)d_in[2];
  const float* W1r = (const float*)d_in[3];
  const float* b1 = (const float*)d_in[4];
  const float* W2l = (const float*)d_in[5];
  const float* W2r = (const float*)d_in[6];
  const float* b2 = (const float*)d_in[7];
  const float* W3l = (const float*)d_in[8];
  const float* W3r = (const float*)d_in[9];
  const float* b3 = (const float*)d_in[10];
  const float* Wal = (const float*)d_in[11];
  const float* War = (const float*)d_in[12];
  const float* ba = (const float*)d_in[13];
  const float* Wsl = (const float*)d_in[14];
  const float* Wsr = (const float*)d_in[15];
  const float* bsx = (const float*)d_in[16];
  const float* Wel = (const float*)d_in[17];
  const float* Wer = (const float*)d_in[18];
  const float* be = (const float*)d_in[19];

  int N = in_sizes[0] / 128;
  int E = in_sizes[1] / 2;
  int NBKT = (N + 255) >> 8;

  char* w = (char*)d_ws;
  auto alloc = [&](size_t b) {
    char* p = w;
    w += (b + 255) & ~(size_t)255;
    return p;
  };
  int* deg = (int*)alloc((size_t)N * 4);
  int* row_start = (int*)alloc((size_t)N * 4);
  float* invd = (float*)alloc((size_t)N * 4);
  int* hist = (int*)alloc((size_t)NBUCK * NB1 * 4);
  int* chunk = (int*)alloc(512 * 4);
  int* csr = (int*)alloc((size_t)E * 4);
  // xb (bf16 x, N*128*2 B) aliases ebuf (E*4 B): ebuf dead after build_k.
  size_t xb_bytes = (size_t)N * 128 * 2;
  size_t ebuf_bytes = (size_t)E * 4;
  char* xb_region = (char*)alloc(xb_bytes > ebuf_bytes ? xb_bytes : ebuf_bytes);
  unsigned* ebuf = (unsigned*)xb_region;
  unsigned short* xb = (unsigned short*)xb_region;
  float* aggbuf = (float*)alloc((size_t)N * 128 * 4);
  float* h_a = (float*)alloc((size_t)N * 128 * 4);
  float* h_b = (float*)alloc((size_t)N * 128 * 4);
  unsigned short* hab = (unsigned short*)alloc((size_t)N * 128 * 2);
  unsigned short* hbb = (unsigned short*)alloc((size_t)N * 128 * 2);
  float* head_lr = (float*)alloc((size_t)N * 16 * 4);
  float* Wcat = (float*)alloc(16 * 128 * 4);
  float* bcat = (float*)alloc(16 * 4);

  int stripe = (((E + NB1 - 1) / NB1) + 255) & ~255;
  int nscan = NBUCK * NB1;
  int nbScan = (nscan + TPB - 1) / TPB;
  int nbNode = (N + 3) / 4;
  int nbM = (N + 63) / 64;
  int nbC = (N * 32 + TPB - 1) / TPB;

  // CSR build — no global atomics
  hist1_k<<<NB1, 256, 0, stream>>>(ei, hist, E, stripe);
  scan1_k<<<nbScan, TPB, 0, stream>>>(hist, hist, chunk, nscan);
  scan2_k<<<1, 512, 0, stream>>>(chunk, nbScan);
  scan3_k<<<nbScan, TPB, 0, stream>>>(hist, chunk, nscan);
  scatter1_k<<<NB1, 256, 0, stream>>>(ei, hist, ebuf, E, stripe);
  build_k<<<NBKT, 256, 0, stream>>>(ebuf, hist, row_start, deg, invd, csr, N, E);

  // bf16 copy of x (after build_k: xb aliases ebuf)
  f2b_k<<<nbC, TPB, 0, stream>>>(x, xb, N * 32);

  // layer 1: x -> h_a (+hab)
  agg128_k<<<nbNode, TPB, 0, stream>>>(xb, csr, row_start, deg, invd, aggbuf, N);
  gemm2_k<<<nbM, TPB, 0, stream>>>(aggbuf, x, W1l, W1r, b1, h_a, hab, N, 1);
  // layer 2: h_a -> h_b (+hbb)
  agg128_k<<<nbNode, TPB, 0, stream>>>(hab, csr, row_start, deg, invd, aggbuf, N);
  gemm2_k<<<nbM, TPB, 0, stream>>>(aggbuf, h_a, W2l, W2r, b2, h_b, hbb, N, 1);
  // layer 3: h_b -> h_a (+hab reused)
  agg128_k<<<nbNode, TPB, 0, stream>>>(hbb, csr, row_start, deg, invd, aggbuf, N);
  gemm2_k<<<nbM, TPB, 0, stream>>>(aggbuf, h_b, W3l, W3r, b3, h_a, hab, N, 1);
  // heads
  pack_head_k<<<8, TPB, 0, stream>>>(Wal, War, ba, Wsl, Wsr, bsx, Wel, Wer, be, Wcat, bcat);
  head_gemm_k<<<nbM, TPB, 0, stream>>>(h_a, Wcat, bcat, head_lr, N);
  agg8_k<<<nbNode, TPB, 0, stream>>>(head_lr, csr, row_start, deg, invd, (float*)d_out, N);
}

// Round 5
// 832.984 us; speedup vs baseline: 2.3661x; 1.1155x over previous
//
#include <hip/hip_runtime.h>

#define TPB 256
#define NB1 256    // stripe blocks for edge passes
#define NBUCK 512  // coarse buckets (dst>>8); supports N <= 131072

using half4_t = __attribute__((ext_vector_type(4))) _Float16;
using half8_t = __attribute__((ext_vector_type(8))) _Float16;
using f32x4 = __attribute__((ext_vector_type(4))) float;

// ---------------- CSR build: atomic-free MSD counting sort ----------------

__global__ __launch_bounds__(256) void hist1_k(const int* __restrict__ ei,
                                               int* __restrict__ hist, int E, int stripe) {
  __shared__ int h[NBUCK];
  for (int i = threadIdx.x; i < NBUCK; i += 256) h[i] = 0;
  __syncthreads();
  int b0 = blockIdx.x * stripe;
  int b1 = min(b0 + stripe, E);
  for (int e = b0 + threadIdx.x; e < b1; e += 256) atomicAdd(&h[ei[E + e] >> 8], 1);
  __syncthreads();
  for (int i = threadIdx.x; i < NBUCK; i += 256) hist[i * NB1 + blockIdx.x] = h[i];
}

__global__ void scan1_k(const int* __restrict__ src, int* __restrict__ out,
                        int* __restrict__ chunk, int n) {
  __shared__ int sh[TPB];
  int i = blockIdx.x * TPB + threadIdx.x;
  int v = (i < n) ? src[i] : 0;
  sh[threadIdx.x] = v;
  __syncthreads();
  for (int off = 1; off < TPB; off <<= 1) {
    int t = (threadIdx.x >= off) ? sh[threadIdx.x - off] : 0;
    __syncthreads();
    sh[threadIdx.x] += t;
    __syncthreads();
  }
  if (i < n) out[i] = sh[threadIdx.x] - v;
  if (threadIdx.x == TPB - 1) chunk[blockIdx.x] = sh[TPB - 1];
}

__global__ void scan2_k(int* __restrict__ chunk, int nb) {
  __shared__ int sh[512];
  int v = (threadIdx.x < nb) ? chunk[threadIdx.x] : 0;
  sh[threadIdx.x] = v;
  __syncthreads();
  for (int off = 1; off < 512; off <<= 1) {
    int t = (threadIdx.x >= off) ? sh[threadIdx.x - off] : 0;
    __syncthreads();
    sh[threadIdx.x] += t;
    __syncthreads();
  }
  if (threadIdx.x < nb) chunk[threadIdx.x] = sh[threadIdx.x] - v;
}

__global__ void scan3_k(int* __restrict__ out, const int* __restrict__ chunk, int n) {
  int i = blockIdx.x * TPB + threadIdx.x;
  if (i < n) out[i] += chunk[blockIdx.x];
}

// pack: src (24 bits) | low8(dst) << 24
__global__ __launch_bounds__(256) void scatter1_k(const int* __restrict__ ei,
                                                  const int* __restrict__ base,
                                                  unsigned* __restrict__ ebuf, int E,
                                                  int stripe) {
  __shared__ int cur[NBUCK];
  for (int i = threadIdx.x; i < NBUCK; i += 256) cur[i] = base[i * NB1 + blockIdx.x];
  __syncthreads();
  int b0 = blockIdx.x * stripe;
  int b1 = min(b0 + stripe, E);
  for (int e = b0 + threadIdx.x; e < b1; e += 256) {
    int s = ei[e];
    int d = ei[E + e];
    int p = atomicAdd(&cur[d >> 8], 1);
    ebuf[p] = (unsigned)s | ((unsigned)(d & 255) << 24);
  }
}

__global__ __launch_bounds__(256) void build_k(const unsigned* __restrict__ ebuf,
                                               const int* __restrict__ base,
                                               int* __restrict__ row_start,
                                               int* __restrict__ deg,
                                               float* __restrict__ invd,
                                               int* __restrict__ csr, int N, int E) {
  __shared__ int h[256];
  __shared__ int excl[256];
  __shared__ int bse[2];
  int b = blockIdx.x;
  int t = threadIdx.x;
  if (t == 0) {
    bse[0] = base[b * NB1];
    bse[1] = (b + 1 < NBUCK) ? base[(b + 1) * NB1] : E;
  }
  h[t] = 0;
  __syncthreads();
  int bs = bse[0], be = bse[1];
  for (int e = bs + t; e < be; e += 256) atomicAdd(&h[ebuf[e] >> 24], 1);
  __syncthreads();
  int v = h[t];
  excl[t] = v;
  __syncthreads();
  for (int off = 1; off < 256; off <<= 1) {
    int tv = (t >= off) ? excl[t - off] : 0;
    __syncthreads();
    excl[t] += tv;
    __syncthreads();
  }
  int ex = excl[t] - v;
  int node = b * 256 + t;
  if (node < N) {
    row_start[node] = bs + ex;
    deg[node] = v;
    invd[node] = 1.0f / fmaxf((float)v, 1.0f);
  }
  h[t] = bs + ex;
  __syncthreads();
  for (int e = bs + t; e < be; e += 256) {
    unsigned p = ebuf[e];
    int pos = atomicAdd(&h[p >> 24], 1);
    csr[pos] = (int)(p & 0xFFFFFFu);
  }
}

// ---------------- fp32 -> fp16 converts ----------------

__global__ void f2h_k(const float* __restrict__ in, _Float16* __restrict__ out, int n4) {
  int i = blockIdx.x * TPB + threadIdx.x;
  if (i < n4) {
    float4 v = ((const float4*)in)[i];
    half4_t o;
    o.x = (_Float16)v.x; o.y = (_Float16)v.y; o.z = (_Float16)v.z; o.w = (_Float16)v.w;
    ((half4_t*)out)[i] = o;
  }
}

// Convert the 6 layer weight matrices (each 128x128) to fp16, packed
// [W1l, W1r, W2l, W2r, W3l, W3r] at 16384-element strides.
__global__ void w6_k(const float* __restrict__ w0, const float* __restrict__ w1,
                     const float* __restrict__ w2, const float* __restrict__ w3,
                     const float* __restrict__ w4, const float* __restrict__ w5,
                     _Float16* __restrict__ out) {
  int t = blockIdx.x * TPB + threadIdx.x;  // t < 6*4096 (float4 units)
  if (t >= 6 * 4096) return;
  int which = t >> 12, i = t & 4095;
  const float* src = which == 0 ? w0 : which == 1 ? w1 : which == 2 ? w2
                   : which == 3 ? w3 : which == 4 ? w4 : w5;
  float4 v = ((const float4*)src)[i];
  half4_t o;
  o.x = (_Float16)v.x; o.y = (_Float16)v.y; o.z = (_Float16)v.z; o.w = (_Float16)v.w;
  ((half4_t*)out)[(size_t)which * 4096 + i] = o;
}

// ---------------- 128-dim mean aggregation, fp16 gather, fp16 out ----------------
// One wave per node; lanes 0-31 even rows, 32-63 odd rows; lane covers 4 features.

__global__ void agg128_k(const _Float16* __restrict__ hb, const int* __restrict__ csr,
                         const int* __restrict__ row_start, const int* __restrict__ deg,
                         const float* __restrict__ invd, _Float16* __restrict__ out,
                         int n) {
  int node = (blockIdx.x << 2) + (threadIdx.x >> 6);
  if (node >= n) return;
  int lane = threadIdx.x & 63;
  int half = lane >> 5;
  int l = lane & 31;
  int s = row_start[node];
  int c = deg[node];
  float a0 = 0.f, a1 = 0.f, a2 = 0.f, a3 = 0.f;
  int j = 0;
  for (; j + 8 <= c; j += 8) {
    int idx[4];
#pragma unroll
    for (int p = 0; p < 4; ++p) idx[p] = csr[s + j + 2 * p + half];
#pragma unroll
    for (int p = 0; p < 4; ++p) {
      half4_t v = *(const half4_t*)&hb[(size_t)idx[p] * 128 + (l << 2)];
      a0 += (float)v.x; a1 += (float)v.y; a2 += (float)v.z; a3 += (float)v.w;
    }
  }
  for (; j + 2 <= c; j += 2) {
    int src = csr[s + j + half];
    half4_t v = *(const half4_t*)&hb[(size_t)src * 128 + (l << 2)];
    a0 += (float)v.x; a1 += (float)v.y; a2 += (float)v.z; a3 += (float)v.w;
  }
  if (j < c && half == 0) {
    int src = csr[s + j];
    half4_t v = *(const half4_t*)&hb[(size_t)src * 128 + (l << 2)];
    a0 += (float)v.x; a1 += (float)v.y; a2 += (float)v.z; a3 += (float)v.w;
  }
  a0 += __shfl_xor(a0, 32);
  a1 += __shfl_xor(a1, 32);
  a2 += __shfl_xor(a2, 32);
  a3 += __shfl_xor(a3, 32);
  if (half == 0) {
    float w = invd[node];
    half4_t r;
    r.x = (_Float16)(a0 * w); r.y = (_Float16)(a1 * w);
    r.z = (_Float16)(a2 * w); r.w = (_Float16)(a3 * w);
    *(half4_t*)&out[(size_t)node * 128 + (l << 2)] = r;
  }
}

// ---------------- fused dual GEMM via f16 MFMA ----------------
// outh = act(Aagg@Wl^T + Ah@Wr^T + b), fp32 accumulate, fp16 store.
// Block: 4 waves; wave = 16-row strip x 128 cols (8 col-tiles of 16x16x32 MFMA).
// A frag: lane holds A[m=lane&15][k=quad*8+j]; B frag: W[o=lane&15 of tile][same k].
// C/D: col=lane&15, row=quad*4+reg (m89-verified).

__global__ __launch_bounds__(256) void gemm2_k(
    const _Float16* __restrict__ Aagg, const _Float16* __restrict__ Ah,
    const _Float16* __restrict__ Wh,  // [2][128][128]: Wl then Wr
    const float* __restrict__ bias, _Float16* __restrict__ outh, int n, int do_relu) {
  int wave = threadIdx.x >> 6;
  int lane = threadIdx.x & 63;
  int quad = lane >> 4;
  int l16 = lane & 15;
  int m0 = blockIdx.x * 64 + wave * 16;
  int arow = m0 + l16;
  bool valid = arow < n;
  size_t abase = (size_t)arow * 128 + quad * 8;

  f32x4 acc[8];
#pragma unroll
  for (int c = 0; c < 8; ++c) acc[c] = (f32x4){0.f, 0.f, 0.f, 0.f};

#pragma unroll
  for (int s = 0; s < 2; ++s) {
    const _Float16* A = s ? Ah : Aagg;
    const _Float16* W = Wh + (size_t)s * 16384;
#pragma unroll
    for (int kb = 0; kb < 128; kb += 32) {
      half8_t af;
      if (valid) {
        af = *(const half8_t*)&A[abase + kb];
      } else {
#pragma unroll
        for (int jj = 0; jj < 8; ++jj) af[jj] = (_Float16)0;
      }
#pragma unroll
      for (int c = 0; c < 8; ++c) {
        half8_t bf = *(const half8_t*)&W[(size_t)(c * 16 + l16) * 128 + kb + quad * 8];
        acc[c] = __builtin_amdgcn_mfma_f32_16x16x32_f16(af, bf, acc[c], 0, 0, 0);
      }
    }
  }

#pragma unroll
  for (int c = 0; c < 8; ++c) {
    float bcol = bias[c * 16 + l16];
#pragma unroll
    for (int r = 0; r < 4; ++r) {
      int row = m0 + quad * 4 + r;
      if (row < n) {
        float v = acc[c][r] + bcol;
        if (do_relu) v = fmaxf(v, 0.f);
        outh[(size_t)row * 128 + c * 16 + l16] = (_Float16)v;
      }
    }
  }
}

// ---------------- head weight packing (fp16 Wcat, fp32 bcat) ----------------

__global__ void pack_head_k(const float* __restrict__ Wal, const float* __restrict__ War,
                            const float* __restrict__ ba, const float* __restrict__ Wsl,
                            const float* __restrict__ Wsr, const float* __restrict__ bsx,
                            const float* __restrict__ Wel, const float* __restrict__ Wer,
                            const float* __restrict__ be, _Float16* __restrict__ Wcat,
                            float* __restrict__ bcat) {
  int t = blockIdx.x * TPB + threadIdx.x;
  float v = 0.f;
  bool ok = t < 2048;
  if (t < 384) v = Wal[t];
  else if (t < 640) v = Wsl[t - 384];
  else if (t < 1024) v = Wel[t - 640];
  else if (t < 1408) v = War[t - 1024];
  else if (t < 1664) v = Wsr[t - 1408];
  else if (t < 2048) v = Wer[t - 1664];
  if (ok) Wcat[t] = (_Float16)v;
  if (t < 16) {
    float b = 0.f;
    if (t >= 8 && t < 11) b = ba[t - 8];
    else if (t >= 11 && t < 13) b = bsx[t - 11];
    else if (t >= 13) b = be[t - 13];
    bcat[t] = b;
  }
}

// ---------------- head GEMM: out_lr[n,16] = h3 @ Wcat^T + bcat (fp16 in) ----------------

__global__ __launch_bounds__(256) void head_gemm_k(const _Float16* __restrict__ h,
                                                   const _Float16* __restrict__ Wcat,
                                                   const float* __restrict__ bcat,
                                                   float* __restrict__ out_lr, int n) {
  __shared__ float hs[64 * 132];
  __shared__ float Ws[16 * 128];
  __shared__ float bsh[16];
  int tid = threadIdx.x;
  int m0 = blockIdx.x * 64;
  {
    half8_t w = *(const half8_t*)&Wcat[tid * 8];
#pragma unroll
    for (int jj = 0; jj < 8; ++jj) Ws[tid * 8 + jj] = (float)w[jj];
    if (tid < 16) bsh[tid] = bcat[tid];
  }
  {
    int row = tid >> 2, q = tid & 3;
    int grow = m0 + row;
#pragma unroll
    for (int j = 0; j < 4; ++j) {
      half8_t v;
      if (grow < n) {
        v = *(const half8_t*)&h[(size_t)grow * 128 + q * 32 + j * 8];
      } else {
#pragma unroll
        for (int jj = 0; jj < 8; ++jj) v[jj] = (_Float16)0;
      }
#pragma unroll
      for (int jj = 0; jj < 8; ++jj) hs[row * 132 + q * 32 + j * 8 + jj] = (float)v[jj];
    }
  }
  __syncthreads();
  int row = tid & 63, og = tid >> 6;
  float acc[4] = {0.f, 0.f, 0.f, 0.f};
#pragma unroll
  for (int k4 = 0; k4 < 32; ++k4) {
    float4 hv = *(float4*)&hs[row * 132 + k4 * 4];
#pragma unroll
    for (int i = 0; i < 4; ++i) {
      float4 wv = *(float4*)&Ws[(og * 4 + i) * 128 + k4 * 4];
      acc[i] += hv.x * wv.x + hv.y * wv.y + hv.z * wv.z + hv.w * wv.w;
    }
  }
  int grow = m0 + row;
  if (grow < n) {
#pragma unroll
    for (int i = 0; i < 4; ++i)
      out_lr[(size_t)grow * 16 + og * 4 + i] = acc[i] + bsh[og * 4 + i];
  }
}

// ---------------- 8-dim aggregation + output write ----------------
// out layout: age [n,3] @0, sex [n,2] @3n, eth [n,3] @5n

__global__ void agg8_k(const float* __restrict__ hlr, const int* __restrict__ csr,
                       const int* __restrict__ row_start, const int* __restrict__ deg,
                       const float* __restrict__ invd, float* __restrict__ out, int n) {
  int node = (blockIdx.x << 2) + (threadIdx.x >> 6);
  if (node >= n) return;
  int lane = threadIdx.x & 63;
  int c = lane & 7, g = lane >> 3;
  int s = row_start[node], cnt = deg[node];
  float acc = 0.f;
  for (int j = g; j < cnt; j += 8) {
    int src = csr[s + j];
    acc += hlr[(size_t)src * 16 + c];
  }
  acc += __shfl_xor(acc, 8);
  acc += __shfl_xor(acc, 16);
  acc += __shfl_xor(acc, 32);
  if (g == 0) {
    float r = acc * invd[node] + hlr[(size_t)node * 16 + 8 + c];
    if (c < 3) out[(size_t)node * 3 + c] = r;
    else if (c < 5) out[(size_t)3 * n + (size_t)node * 2 + (c - 3)] = r;
    else out[(size_t)5 * n + (size_t)node * 3 + (c - 5)] = r;
  }
}

// ---------------- launch ----------------

extern "C" void kernel_launch(void* const* d_in, const int* in_sizes, int n_in,
                              void* d_out, int out_size, void* d_ws, size_t ws_size,
                              hipStream_t stream) {
  const float* x = (const float*)d_in[0];
  const int* ei = (const int*)d_in[1];
  const float* W1l = (const float*)d_in[2];
  const float* W1r = (const float*)d_in[3];
  const float* b1 = (const float*)d_in[4];
  const float* W2l = (const float*)d_in[5];
  const float* W2r = (const float*)d_in[6];
  const float* b2 = (const float*)d_in[7];
  const float* W3l = (const float*)d_in[8];
  const float* W3r = (const float*)d_in[9];
  const float* b3 = (const float*)d_in[10];
  const float* Wal = (const float*)d_in[11];
  const float* War = (const float*)d_in[12];
  const float* ba = (const float*)d_in[13];
  const float* Wsl = (const float*)d_in[14];
  const float* Wsr = (const float*)d_in[15];
  const float* bsx = (const float*)d_in[16];
  const float* Wel = (const float*)d_in[17];
  const float* Wer = (const float*)d_in[18];
  const float* be = (const float*)d_in[19];

  int N = in_sizes[0] / 128;
  int E = in_sizes[1] / 2;
  int NBKT = (N + 255) >> 8;

  char* w = (char*)d_ws;
  auto alloc = [&](size_t b) {
    char* p = w;
    w += (b + 255) & ~(size_t)255;
    return p;
  };
  int* deg = (int*)alloc((size_t)N * 4);
  int* row_start = (int*)alloc((size_t)N * 4);
  float* invd = (float*)alloc((size_t)N * 4);
  int* hist = (int*)alloc((size_t)NBUCK * NB1 * 4);
  int* chunk = (int*)alloc(512 * 4);
  int* csr = (int*)alloc((size_t)E * 4);
  // xh (fp16 x, N*128*2 B) aliases ebuf (E*4 B): ebuf dead after build_k.
  size_t xh_bytes = (size_t)N * 128 * 2;
  size_t ebuf_bytes = (size_t)E * 4;
  char* region = (char*)alloc(xh_bytes > ebuf_bytes ? xh_bytes : ebuf_bytes);
  unsigned* ebuf = (unsigned*)region;
  _Float16* xh = (_Float16*)region;
  _Float16* aggh = (_Float16*)alloc((size_t)N * 128 * 2);
  _Float16* hA = (_Float16*)alloc((size_t)N * 128 * 2);
  _Float16* hB = (_Float16*)alloc((size_t)N * 128 * 2);
  _Float16* wh = (_Float16*)alloc((size_t)6 * 16384 * 2);
  _Float16* Wcat = (_Float16*)alloc(2048 * 2);
  float* bcat = (float*)alloc(16 * 4);
  float* head_lr = (float*)alloc((size_t)N * 16 * 4);

  int stripe = (((E + NB1 - 1) / NB1) + 255) & ~255;
  int nscan = NBUCK * NB1;
  int nbScan = (nscan + TPB - 1) / TPB;
  int nbNode = (N + 3) / 4;
  int nbM = (N + 63) / 64;
  int nbC = (N * 32 + TPB - 1) / TPB;

  // CSR build — no global atomics
  hist1_k<<<NB1, 256, 0, stream>>>(ei, hist, E, stripe);
  scan1_k<<<nbScan, TPB, 0, stream>>>(hist, hist, chunk, nscan);
  scan2_k<<<1, 512, 0, stream>>>(chunk, nbScan);
  scan3_k<<<nbScan, TPB, 0, stream>>>(hist, chunk, nscan);
  scatter1_k<<<NB1, 256, 0, stream>>>(ei, hist, ebuf, E, stripe);
  build_k<<<NBKT, 256, 0, stream>>>(ebuf, hist, row_start, deg, invd, csr, N, E);

  // fp16 conversions (xh aliases ebuf: must come after build_k)
  f2h_k<<<nbC, TPB, 0, stream>>>(x, xh, N * 32);
  w6_k<<<96, TPB, 0, stream>>>(W1l, W1r, W2l, W2r, W3l, W3r, wh);
  pack_head_k<<<8, TPB, 0, stream>>>(Wal, War, ba, Wsl, Wsr, bsx, Wel, Wer, be, Wcat, bcat);

  // layer 1: x -> hA
  agg128_k<<<nbNode, TPB, 0, stream>>>(xh, csr, row_start, deg, invd, aggh, N);
  gemm2_k<<<nbM, TPB, 0, stream>>>(aggh, xh, wh + 0 * 16384, b1, hA, N, 1);
  // layer 2: hA -> hB
  agg128_k<<<nbNode, TPB, 0, stream>>>(hA, csr, row_start, deg, invd, aggh, N);
  gemm2_k<<<nbM, TPB, 0, stream>>>(aggh, hA, wh + 2 * 16384, b2, hB, N, 1);
  // layer 3: hB -> hA (hA layer-1 copy dead)
  agg128_k<<<nbNode, TPB, 0, stream>>>(hB, csr, row_start, deg, invd, aggh, N);
  gemm2_k<<<nbM, TPB, 0, stream>>>(aggh, hB, wh + 4 * 16384, b3, hA, N, 1);
  // heads: transform to 16 dims first, then aggregate
  head_gemm_k<<<nbM, TPB, 0, stream>>>(hA, Wcat, bcat, head_lr, N);
  agg8_k<<<nbNode, TPB, 0, stream>>>(head_lr, csr, row_start, deg, invd, (float*)d_out, N);
}